// Round 3
// baseline (413.819 us; speedup 1.0000x reference)
//
#include <hip/hip_runtime.h>

// TAACTD loss: reverse-time affine recurrence over T=256, B=65536.
// out[t] = (ret_t - value[t])^2 for t in [0, T-2]; out[T-1] = 0.
// ret_t = acc_{t+1} * (discount[t+1]*GAMMA) + reward[t+1]
// acc_t = il_t ? target_value[t] : ret_t
// il_t  = (step_type[t]==2) | ((t>0) & (rollout_b[t]|b[t]))
//
// Round 3: latency-bound fix, attempt 2.
//  - float2/int2: 2 cols per lane -> each load instr carries 512 B/wave,
//    doubling bytes-in-flight per vmcnt slot (vmcnt caps at 63 instrs).
//  - __launch_bounds__(64, 1): allow up to 512 VGPRs so the D=5 rotating
//    prefetch buffer (70 regs) stays live instead of collapsing (round 2:
//    VGPR=68 proved the compiler killed the pipeline).
//  - 512 blocks x 64 threads = 2 waves/CU on all 256 CUs.
//  - D=5 divides NSTEP=255 exactly: no tail loop.

#define GAMMA_F 0.98f

constexpr int T = 256;
constexpr int B = 65536;
constexpr int S = B / 2;      // row stride in float2 units = 32768
constexpr int NSTEP = T - 1;  // 255 steps: t = 254 .. 0
constexpr int D = 5;          // prefetch depth; 255 % 5 == 0 (no tail)

__global__ __launch_bounds__(64, 1) void td_loss_kernel(
    const float* __restrict__ reward,
    const float* __restrict__ discount,
    const float* __restrict__ value,
    const float* __restrict__ target_value,
    const int*   __restrict__ b_arr,
    const int*   __restrict__ rollout_b,
    const int*   __restrict__ step_type,
    float*       __restrict__ out)
{
    const int lane = blockIdx.x * 64 + threadIdx.x;  // 0 .. 32767

    const float2* rw2 = (const float2*)reward;
    const float2* dc2 = (const float2*)discount;
    const float2* vl2 = (const float2*)value;
    const float2* tv2 = (const float2*)target_value;
    const int2*   b2  = (const int2*)b_arr;
    const int2*   rb2 = (const int2*)rollout_b;
    const int2*   st2 = (const int2*)step_type;
    float2*       ot2 = (float2*)out;

    // rotating prefetch buffers (slot j holds data for step s, s % D == j)
    float2 pd[D], pr[D], pv[D], pt[D];
    int2   pb[D], prb[D], pst[D];

    float2 acc = tv2[(size_t)(T - 1) * S + lane];
    ot2[(size_t)(T - 1) * S + lane] = make_float2(0.0f, 0.0f);  // poisoned out

    // prologue: fill all D slots (steps s = 0..D-1, i.e. t = 254..250)
    #pragma unroll
    for (int j = 0; j < D; ++j) {
        const int t = NSTEP - 1 - j;
        const size_t it = (size_t)t * S + lane;
        pd[j]  = dc2[it + S];
        pr[j]  = rw2[it + S];
        pv[j]  = vl2[it];
        pt[j]  = tv2[it];
        pb[j]  = b2[it];
        prb[j] = rb2[it];
        pst[j] = st2[it];
    }

    // main loop: 51 outer iterations x 5 steps, s = 0 .. 254 (all steps)
    #pragma unroll 1
    for (int s0 = 0; s0 < NSTEP; s0 += D) {
        #pragma unroll
        for (int j = 0; j < D; ++j) {
            const int s = s0 + j;
            const int t = NSTEP - 1 - s;

            // ---- consume slot j (step s) ----
            const float dx = pd[j].x * GAMMA_F;
            const float dy = pd[j].y * GAMMA_F;
            const float retx = acc.x * dx + pr[j].x;
            const float rety = acc.y * dy + pr[j].y;
            const bool ilx = (pst[j].x == 2) || ((t > 0) && ((pb[j].x | prb[j].x) != 0));
            const bool ily = (pst[j].y == 2) || ((t > 0) && ((pb[j].y | prb[j].y) != 0));
            acc.x = ilx ? pt[j].x : retx;
            acc.y = ily ? pt[j].y : rety;
            const float ddx = retx - pv[j].x;
            const float ddy = rety - pv[j].y;
            ot2[(size_t)t * S + lane] = make_float2(ddx * ddx, ddy * ddy);

            // ---- prefetch step s + D into slot j ----
            const int sp = s + D;
            if (sp < NSTEP) {
                const int tp = NSTEP - 1 - sp;
                const size_t it = (size_t)tp * S + lane;
                pd[j]  = dc2[it + S];
                pr[j]  = rw2[it + S];
                pv[j]  = vl2[it];
                pt[j]  = tv2[it];
                pb[j]  = b2[it];
                prb[j] = rb2[it];
                pst[j] = st2[it];
            }
        }
    }
}

extern "C" void kernel_launch(void* const* d_in, const int* in_sizes, int n_in,
                              void* d_out, int out_size, void* d_ws, size_t ws_size,
                              hipStream_t stream) {
    const float* reward       = (const float*)d_in[0];
    const float* discount     = (const float*)d_in[1];
    const float* value        = (const float*)d_in[2];
    const float* target_value = (const float*)d_in[3];
    const int*   b_arr        = (const int*)d_in[4];
    const int*   rollout_b    = (const int*)d_in[5];
    const int*   step_type    = (const int*)d_in[6];
    float*       out          = (float*)d_out;

    // 32768 lanes (2 cols each), 64-thread blocks -> 512 blocks -> 2 waves/CU
    const int threads = 64;
    const int blocks  = (B / 2) / threads;  // 512
    td_loss_kernel<<<blocks, threads, 0, stream>>>(
        reward, discount, value, target_value, b_arr, rollout_b, step_type, out);
}

// Round 6
// 406.105 us; speedup vs baseline: 1.0190x; 1.0190x over previous
//
#include <hip/hip_runtime.h>

// TAACTD loss: reverse-time affine recurrence over T=256, B=65536.
// out[t] = (ret_t - value[t])^2 for t in [0, T-2]; out[T-1] = 0.
// ret_t = acc_{t+1} * (discount[t+1]*GAMMA) + reward[t+1]
// acc_t = il_t ? target_value[t] : ret_t
// il_t  = (step_type[t]==2) | ((t>0) & (rollout_b[t]|b[t]))
//
// Round 6: software pipeline WITHOUT inline-asm loads (rounds 4-5's asm
// kernels aborted; rounds 1-3 plain HIP all ran). The collapse mechanism
// (VGPR 68->44) was the MachineScheduler sinking prefetch loads to their
// uses in the unrolled block. Fix: __builtin_amdgcn_sched_barrier(0)
// fences between every CONSUME and PREFETCH region — side-effecting, so
// no IR pass or scheduler may move loads across. Loads stay plain HIP,
// so SIInsertWaitcnts still emits precise counted vmcnt(N) at first use:
// round-4 pipeline semantics, zero asm. D=5 slots, 7 float2 loads/step
// -> issue 5 steps ahead, implicit steady-state wait = vmcnt(28).
// 2 waves/CU x 28 loads x 512 B ≈ 28 KB in flight per CU (need ~10.6 KB).

#define GAMMA_F 0.98f

constexpr int T = 256;
constexpr int B = 65536;
constexpr int S = B / 2;      // row stride in float2 units
constexpr int D = 5;          // prefetch depth; 255 = 51*5

typedef float f32x2 __attribute__((ext_vector_type(2)));
typedef int   i32x2 __attribute__((ext_vector_type(2)));

#define SB() __builtin_amdgcn_sched_barrier(0)

// issue the 7 plain loads for time-step t into slot j (j literal)
#define PREFETCH(j, t) do {                  \
    const size_t it_ = (size_t)(t) * S + lane; \
    pd[j]  = dc2[it_ + S];                   \
    pr[j]  = rw2[it_ + S];                   \
    pv[j]  = vl2[it_];                       \
    pt[j]  = tv2[it_];                       \
    pb[j]  = b2[it_];                        \
    prb[j] = rb2[it_];                       \
    pst[j] = st2[it_];                       \
} while (0)

// consume slot j for time-step t; T0 = (t > 0) as a literal
#define CONSUME(j, t, T0) do {                                      \
    const float retx_ = acc.x * (pd[j].x * GAMMA_F) + pr[j].x;      \
    const float rety_ = acc.y * (pd[j].y * GAMMA_F) + pr[j].y;      \
    const bool ilx_ = (pst[j].x == 2) || ((T0) && ((pb[j].x | prb[j].x) != 0)); \
    const bool ily_ = (pst[j].y == 2) || ((T0) && ((pb[j].y | prb[j].y) != 0)); \
    acc.x = ilx_ ? pt[j].x : retx_;                                 \
    acc.y = ily_ ? pt[j].y : rety_;                                 \
    f32x2 o_;                                                       \
    o_.x = (retx_ - pv[j].x) * (retx_ - pv[j].x);                   \
    o_.y = (rety_ - pv[j].y) * (rety_ - pv[j].y);                   \
    ot2[(size_t)(t) * S + lane] = o_;                               \
} while (0)

// one pipelined step: consume slot j at time t, then refill it with t-D
#define STEP(j, t) do {                      \
    SB(); CONSUME(j, (t), true);             \
    SB(); PREFETCH(j, (t) - D);              \
} while (0)

__global__ __launch_bounds__(64, 1) void td_loss_kernel(
    const float* __restrict__ reward,
    const float* __restrict__ discount,
    const float* __restrict__ value,
    const float* __restrict__ target_value,
    const int*   __restrict__ b_arr,
    const int*   __restrict__ rollout_b,
    const int*   __restrict__ step_type,
    float*       __restrict__ out)
{
    const int lane = blockIdx.x * 64 + threadIdx.x;  // 0..32767

    const f32x2* rw2 = (const f32x2*)reward;
    const f32x2* dc2 = (const f32x2*)discount;
    const f32x2* vl2 = (const f32x2*)value;
    const f32x2* tv2 = (const f32x2*)target_value;
    const i32x2* b2  = (const i32x2*)b_arr;
    const i32x2* rb2 = (const i32x2*)rollout_b;
    const i32x2* st2 = (const i32x2*)step_type;
    f32x2*       ot2 = (f32x2*)out;

    f32x2 pd[D], pr[D], pv[D], pt[D];
    i32x2 pb[D], prb[D], pst[D];

    f32x2 acc = tv2[(size_t)(T - 1) * S + lane];

    // last output row must be 0 (d_out is poisoned before every launch)
    f32x2 z_; z_.x = 0.0f; z_.y = 0.0f;
    ot2[(size_t)(T - 1) * S + lane] = z_;

    // prologue: fill slots 0..4 with t = 254..250
    SB();
    PREFETCH(0, 254); PREFETCH(1, 253); PREFETCH(2, 252);
    PREFETCH(3, 251); PREFETCH(4, 250);

    // steady state: 50 outer iterations, t0 = 254, 249, ..., 9.
    // Each STEP consumes a slot loaded 5 steps earlier (28 newer loads in
    // flight -> compiler inserts counted vmcnt, never a drain).
    #pragma unroll 1
    for (int s0 = 0; s0 < 250; s0 += 5) {
        const int t0 = 254 - s0;
        STEP(0, t0);
        STEP(1, t0 - 1);
        STEP(2, t0 - 2);
        STEP(3, t0 - 3);
        STEP(4, t0 - 4);
    }

    // tail: t = 4..0, consume remaining slots, no prefetch
    SB(); CONSUME(0, 4, true);
    SB(); CONSUME(1, 3, true);
    SB(); CONSUME(2, 2, true);
    SB(); CONSUME(3, 1, true);
    SB(); CONSUME(4, 0, false);   // t==0: bb forced false
}

extern "C" void kernel_launch(void* const* d_in, const int* in_sizes, int n_in,
                              void* d_out, int out_size, void* d_ws, size_t ws_size,
                              hipStream_t stream) {
    const float* reward       = (const float*)d_in[0];
    const float* discount     = (const float*)d_in[1];
    const float* value        = (const float*)d_in[2];
    const float* target_value = (const float*)d_in[3];
    const int*   b_arr        = (const int*)d_in[4];
    const int*   rollout_b    = (const int*)d_in[5];
    const int*   step_type    = (const int*)d_in[6];
    float*       out          = (float*)d_out;

    // 32768 lanes (2 cols each), 64-thread blocks -> 512 blocks = 2 waves/CU
    const int threads = 64;
    const int blocks  = (B / 2) / threads;  // 512
    td_loss_kernel<<<blocks, threads, 0, stream>>>(
        reward, discount, value, target_value, b_arr, rollout_b, step_type, out);
}